// Round 7
// baseline (249.671 us; speedup 1.0000x reference)
//
#include <hip/hip_runtime.h>

#define TT 512
#define LOG2E 1.44269504088896340736f

// ---- DPP helpers (rows of 16 lanes) ----
__device__ __forceinline__ int rori_(int v) {            // row_ror:1, in-place tie
    return __builtin_amdgcn_update_dpp(v, v, 0x121, 0xf, 0xf, true);
}
__device__ __forceinline__ int ror4i_(int v) {           // row_ror:4
    return __builtin_amdgcn_update_dpp(v, v, 0x124, 0xf, 0xf, true);
}
__device__ __forceinline__ int ror8i_(int v) {           // row_ror:8
    return __builtin_amdgcn_update_dpp(v, v, 0x128, 0xf, 0xf, true);
}
__device__ __forceinline__ float rorf_(float v)  { return __int_as_float(rori_(__float_as_int(v))); }
__device__ __forceinline__ float ror4f_(float v) { return __int_as_float(ror4i_(__float_as_int(v))); }
__device__ __forceinline__ float ror8f_(float v) { return __int_as_float(ror8i_(__float_as_int(v))); }
template <int C>
__device__ __forceinline__ float shrf_(float v) {        // row_shr:N, shifted-in -> 0
    return __int_as_float(__builtin_amdgcn_update_dpp(0, __float_as_int(v), C, 0xf, 0xf, true));
}
__device__ __forceinline__ float sgm_(float v) {         // sigmoid, arg pre-scaled by log2e
    return __builtin_amdgcn_rcpf(1.f + __builtin_amdgcn_exp2f(-v));
}
__device__ __forceinline__ float pswap_(float v) {       // partner half (lane^16) value
    return __shfl_xor(v, 16, 64);
}

__launch_bounds__(64)
__attribute__((amdgpu_waves_per_eu(2)))      // fit 2 waves/SIMD (<=256 VGPR)
__global__ void gru_split(const float* __restrict__ x,
                          const float* __restrict__ W1, const float* __restrict__ Ur1,
                          const float* __restrict__ b1,
                          const float* __restrict__ W2, const float* __restrict__ Ur2,
                          const float* __restrict__ b2,
                          const float* __restrict__ Wd, const float* __restrict__ bd,
                          const float* __restrict__ Wo, const float* __restrict__ bo,
                          float* __restrict__ out)
{
    const int lane   = threadIdx.x & 63;
    const int j      = lane & 15;        // GRU2 / dense unit
    const int u1     = j & 7;            // GRU1 unit (pair-duplicated in 16-row)
    const int hi     = j >> 3;           // z-side / r-side of GRU1 pair
    const int half   = (lane >> 4) & 1;  // tap-half: 0 -> taps 0..7, 1 -> taps 8..15
    const int rowloc = lane >> 5;        // batch row within wave (0/1)
    const bool ishi  = (hi != 0);
    const bool isB   = (half != 0);
    const bool isw   = ((lane & 31) == 15);   // j==15 && half==0 (per row)
    const int row    = blockIdx.x * 2 + rowloc;

    const float* xbase = x + (size_t)blockIdx.x * 2 * TT * 8;
    const int    xoff  = rowloc * TT * 8 + u1;
    float* outrow = out + (size_t)row * TT;

    // ---- trace the DPP permutations incl. the conditional half-starts ----
    int K2[8], K1[4];
    {
        int L  = j;
        int S2 = isB ? ror8i_(L) : L;    // 16-ring start
        int S1 = isB ? ror4i_(L) : L;    // 8-ring start
        K2[0] = S2;
        int t = S2;
#pragma unroll
        for (int k = 1; k < 8; ++k) { t = rori_(t); K2[k] = t; }
        K1[0] = S1;
        t = S1;
#pragma unroll
        for (int k = 1; k < 4; ++k) { t = rori_(t); K1[k] = t; }
    }

    // ---- weights (rotation-ordered per half; z/r pre-scaled by log2e) ----
    float q2z[8], q2r[8], q2h[8], wdk[8];          // rh2 ring, this half's 8 taps
#pragma unroll
    for (int k = 0; k < 8; ++k) {
        const int s2 = K2[k];
        q2z[k] = LOG2E * Ur2[s2 * 48 + j];
        q2r[k] = LOG2E * Ur2[s2 * 48 + 16 + j];
        q2h[k] = Ur2[s2 * 48 + 32 + j];
        wdk[k] = Wd[s2 * 16 + j];
    }
    float p2z[4], p2r[4], p2h[4], Ch[4], Qh[4];    // rn1 ring, 4 taps
    float Ax[4], Wx[4];                            // rx ring, 4 taps
#pragma unroll
    for (int k = 0; k < 4; ++k) {
        const int s1 = K1[k] & 7;
        p2z[k] = LOG2E * W2[s1 * 48 + j];
        p2r[k] = LOG2E * W2[s1 * 48 + 16 + j];
        p2h[k] = W2[s1 * 48 + 32 + j];
        Ch[k]  = LOG2E * Ur1[s1 * 24 + (u1 + 8 * hi)];
        Qh[k]  = Ur1[s1 * 24 + 16 + u1];
        Ax[k]  = LOG2E * W1[s1 * 24 + (u1 + 8 * hi)];
        Wx[k]  = W1[s1 * 24 + 16 + u1];
    }
    // biases: added once per row -> gated to half 0 only
    const float bAzrH = isB ? 0.f : LOG2E * (b1[u1 + 8 * hi] + b1[24 + u1 + 8 * hi]);
    const float bGhH  = isB ? 0.f : b1[16 + u1];
    const float bIhH  = isB ? 0.f : b1[40 + u1];
    const float bA2H  = isB ? 0.f : LOG2E * (b2[j] + b2[48 + j]);
    const float bB2H  = isB ? 0.f : LOG2E * (b2[16 + j] + b2[64 + j]);
    const float bC2H  = isB ? 0.f : b2[80 + j];
    const float bD2H  = isB ? 0.f : b2[32 + j];
    const float bdjH  = isB ? 0.f : bd[j];
    const float woj   = Wo[j], boo = bo[0];

    float h1own = 0.f, h2own = 0.f;
    float azrP = bAzrH, ihP = bIhH;          // carried GRU1 half-partials

    // x slots, 3 steps ahead
    float xA = xbase[0 * 8 + xoff];
    float xB = xbase[1 * 8 + xoff];
    float xC = xbase[2 * 8 + xoff];

#define GSTEP(SS, XCUR, XFILL)                                                  \
    {                                                                           \
        const int s = (SS);                                                     \
        /* ih combine can start immediately (carried partial) */                \
        const float ihC = ihP + pswap_(ihP);                                    \
        /* rx ring: 4 x-taps into azr (z|r) and ghx (candidate) */              \
        float rx  = isB ? ror4f_(XCUR) : XCUR;                                  \
        float azr = azrP, ghx = bGhH;                                           \
        azr = fmaf(rx, Ax[0], azr);  ghx = fmaf(rx, Wx[0], ghx);                \
        _Pragma("unroll")                                                       \
        for (int k = 1; k < 4; ++k) {                                           \
            rx  = rorf_(rx);                                                    \
            azr = fmaf(rx, Ax[k], azr);  ghx = fmaf(rx, Wx[k], ghx);            \
        }                                                                       \
        const float azrC = azr + pswap_(azr);                                   \
        const float ghxC = ghx + pswap_(ghx);                                   \
        /* rh2 ring: 8 taps into GRU2 gates + dense (covers combine latency) */ \
        float rh2 = isB ? ror8f_(h2own) : h2own;                                \
        float za = bA2H, ra = bB2H, ha = bC2H, da = bdjH;                       \
        za = fmaf(rh2, q2z[0], za);  ra = fmaf(rh2, q2r[0], ra);                \
        ha = fmaf(rh2, q2h[0], ha);  da = fmaf(rh2, wdk[0], da);                \
        _Pragma("unroll")                                                       \
        for (int k = 1; k < 8; ++k) {                                           \
            rh2 = rorf_(rh2);                                                   \
            za = fmaf(rh2, q2z[k], za);  ra = fmaf(rh2, q2r[k], ra);            \
            ha = fmaf(rh2, q2h[k], ha);  da = fmaf(rh2, wdk[k], da);            \
        }                                                                       \
        XFILL = xbase[((s + 3) & (TT - 1)) * 8 + xoff];  /* prefetch s+3 */     \
        /* GRU1: pair swap gives both z and r pre-activations */                \
        const float swp = ror8f_(azrC);                                         \
        const float s_own = sgm_(azrC), s_sw = sgm_(swp);                       \
        const float z1 = ishi ? s_sw : s_own;                                   \
        const float r1 = ishi ? s_own : s_sw;                                   \
        const float hh1 = fmaxf(fmaf(r1, ihC, ghxC), 0.f);                      \
        h1own = fmaf(z1, h1own - hh1, hh1);                                     \
        /* rn1 ring: W2 taps + next-step GRU1 h-taps (4 taps/half) */           \
        float rn1 = isB ? ror4f_(h1own) : h1own;                                \
        float hb = bD2H, azrN = bAzrH, ihN = bIhH;                              \
        za   = fmaf(rn1, p2z[0], za);  ra  = fmaf(rn1, p2r[0], ra);             \
        hb   = fmaf(rn1, p2h[0], hb);                                           \
        azrN = fmaf(rn1, Ch[0], azrN); ihN = fmaf(rn1, Qh[0], ihN);             \
        _Pragma("unroll")                                                       \
        for (int k = 1; k < 4; ++k) {                                           \
            rn1  = rorf_(rn1);                                                  \
            za   = fmaf(rn1, p2z[k], za);  ra  = fmaf(rn1, p2r[k], ra);         \
            hb   = fmaf(rn1, p2h[k], hb);                                       \
            azrN = fmaf(rn1, Ch[k], azrN); ihN = fmaf(rn1, Qh[k], ihN);         \
        }                                                                       \
        azrP = azrN; ihP = ihN;                                                 \
        /* combine the 5 GRU2/dense half-partials */                            \
        const float zaC = za + pswap_(za);                                      \
        const float raC = ra + pswap_(ra);                                      \
        const float haC = ha + pswap_(ha);                                      \
        const float hbC = hb + pswap_(hb);                                      \
        const float daC = da + pswap_(da);                                      \
        /* GRU2 nonlinearity + state */                                         \
        const float z2 = sgm_(zaC), r2 = sgm_(raC);                             \
        const float hh2 = fmaxf(fmaf(r2, haC, hbC), 0.f);                       \
        h2own = fmaf(z2, h2own - hh2, hh2);                                     \
        /* dense for step s-1 (daC used h2(s-1)) */                             \
        float e = fmaxf(daC, 0.f) * woj;                                        \
        e += shrf_<0x118>(e);                                                   \
        e += shrf_<0x114>(e);                                                   \
        e += shrf_<0x112>(e);                                                   \
        e += shrf_<0x111>(e);                                                   \
        if (s > 0) { if (isw) outrow[s - 1] = e + boo; }                        \
    }

    for (int s0 = 0; s0 < TT; s0 += 4) {
        GSTEP(s0 + 0, xA, xA)
        GSTEP(s0 + 1, xB, xB)
        GSTEP(s0 + 2, xC, xC)
        GSTEP(s0 + 3, xA, xA)
        { float t = xB; xB = xC; xC = xA; xA = t; }
    }
#undef GSTEP

    // epilogue: dense for s = 511 from final h2
    {
        float rh2 = isB ? ror8f_(h2own) : h2own;
        float da  = fmaf(rh2, wdk[0], bdjH);
#pragma unroll
        for (int k = 1; k < 8; ++k) {
            rh2 = rorf_(rh2);
            da  = fmaf(rh2, wdk[k], da);
        }
        const float daC = da + pswap_(da);
        float e = fmaxf(daC, 0.f) * woj;
        e += shrf_<0x118>(e);
        e += shrf_<0x114>(e);
        e += shrf_<0x112>(e);
        e += shrf_<0x111>(e);
        if (isw) outrow[TT - 1] = e + boo;
    }
}

extern "C" void kernel_launch(void* const* d_in, const int* in_sizes, int n_in,
                              void* d_out, int out_size, void* d_ws, size_t ws_size,
                              hipStream_t stream) {
    const float* x   = (const float*)d_in[0];
    const float* W1  = (const float*)d_in[1];
    const float* Ur1 = (const float*)d_in[2];
    const float* b1  = (const float*)d_in[3];
    const float* W2  = (const float*)d_in[4];
    const float* Ur2 = (const float*)d_in[5];
    const float* b2  = (const float*)d_in[6];
    const float* Wd  = (const float*)d_in[7];
    const float* bd  = (const float*)d_in[8];
    const float* Wo  = (const float*)d_in[9];
    const float* bo  = (const float*)d_in[10];
    float* out = (float*)d_out;

    dim3 grid(4096 / 2);   // 2048 blocks x 1 wave = 2048 waves = 2/SIMD
    dim3 block(64);        // 2 rows x (16 lanes x 2 tap-halves), zero LDS
    gru_split<<<grid, block, 0, stream>>>(x, W1, Ur1, b1, W2, Ur2, b2,
                                          Wd, bd, Wo, bo, out);
}

// Round 8
// 206.725 us; speedup vs baseline: 1.2077x; 1.2077x over previous
//
#include <hip/hip_runtime.h>

#define TT 512
#define LOG2E 1.44269504088896340736f

// ---- DPP helpers (rows of 16 lanes) ----
template <int N>
__device__ __forceinline__ int rorki_(int v) {           // row_ror:N, depth-1 fan-out
    return __builtin_amdgcn_update_dpp(v, v, 0x120 + N, 0xf, 0xf, true);
}
template <int N>
__device__ __forceinline__ float rorkf_(float v) { return __int_as_float(rorki_<N>(__float_as_int(v))); }
template <int C>
__device__ __forceinline__ float shrf_(float v) {        // row_shr:N, shifted-in -> 0
    return __int_as_float(__builtin_amdgcn_update_dpp(0, __float_as_int(v), C, 0xf, 0xf, true));
}
__device__ __forceinline__ float sgm_(float v) {         // sigmoid, arg pre-scaled by log2e
    return __builtin_amdgcn_rcpf(1.f + __builtin_amdgcn_exp2f(-v));
}

__launch_bounds__(64)
__attribute__((amdgpu_waves_per_eu(1, 1)))
__global__ void gru_fan(const float* __restrict__ x,
                        const float* __restrict__ W1, const float* __restrict__ Ur1,
                        const float* __restrict__ b1,
                        const float* __restrict__ W2, const float* __restrict__ Ur2,
                        const float* __restrict__ b2,
                        const float* __restrict__ Wd, const float* __restrict__ bd,
                        const float* __restrict__ Wo, const float* __restrict__ bo,
                        float* __restrict__ out)
{
    const int lane = threadIdx.x & 63;
    const int g    = lane >> 4;         // 16-lane row group -> batch row
    const int j    = lane & 15;         // GRU2 / dense unit
    const int u1   = j & 7;             // GRU1 unit (pair-duplicated)
    const int hi   = j >> 3;            // 0: z-side, 1: r-side of the GRU1 pair
    const int gcol = u1 + 8 * hi;       // z column (0..7) or r column (8..15)
    const int row  = blockIdx.x * 4 + g;
    const bool ishi = (hi != 0);
    const bool isw  = (j == 15);

    const float* xbase = x + (size_t)blockIdx.x * 4 * TT * 8;
    const int    xoff  = g * TT * 8 + u1;
    float* outrow = out + (size_t)row * TT;

    // ---- trace the DIRECT ror:k permutation (layout-proof weight order) ----
    int Lk[16];
    Lk[0]  = j;
    Lk[1]  = rorki_<1>(j);   Lk[2]  = rorki_<2>(j);   Lk[3]  = rorki_<3>(j);
    Lk[4]  = rorki_<4>(j);   Lk[5]  = rorki_<5>(j);   Lk[6]  = rorki_<6>(j);
    Lk[7]  = rorki_<7>(j);   Lk[8]  = rorki_<8>(j);   Lk[9]  = rorki_<9>(j);
    Lk[10] = rorki_<10>(j);  Lk[11] = rorki_<11>(j);  Lk[12] = rorki_<12>(j);
    Lk[13] = rorki_<13>(j);  Lk[14] = rorki_<14>(j);  Lk[15] = rorki_<15>(j);

    // ---- weights (ror:k-ordered; z/r pre-scaled by log2e) ----
    float q2z[16], q2r[16], q2h[16], wdk[16];      // h2 fan (16 taps)
#pragma unroll
    for (int k = 0; k < 16; ++k) {
        const int s2 = Lk[k];
        q2z[k] = LOG2E * Ur2[s2 * 48 + j];
        q2r[k] = LOG2E * Ur2[s2 * 48 + 16 + j];
        q2h[k] = Ur2[s2 * 48 + 32 + j];
        wdk[k] = Wd[s2 * 16 + j];
    }
    float p2z[8], p2r[8], p2h[8], Ch[8], Qh[8];    // h1 fan (8 taps)
    float Ax[8], Wx[8];                            // x fan (8 taps)
#pragma unroll
    for (int k = 0; k < 8; ++k) {
        const int s1 = Lk[k] & 7;
        p2z[k] = LOG2E * W2[s1 * 48 + j];
        p2r[k] = LOG2E * W2[s1 * 48 + 16 + j];
        p2h[k] = W2[s1 * 48 + 32 + j];
        Ch[k]  = LOG2E * Ur1[s1 * 24 + gcol];
        Qh[k]  = Ur1[s1 * 24 + 16 + u1];
        Ax[k]  = LOG2E * W1[s1 * 24 + gcol];
        Wx[k]  = W1[s1 * 24 + 16 + u1];
    }
    const float bAzr = LOG2E * (b1[gcol] + b1[24 + gcol]);
    const float bGh  = b1[16 + u1];
    const float bIh  = b1[40 + u1];
    const float bA2  = LOG2E * (b2[j] + b2[48 + j]);
    const float bB2  = LOG2E * (b2[16 + j] + b2[64 + j]);
    const float bC2  = b2[80 + j];
    const float bD2  = b2[32 + j];
    const float bdj  = bd[j], woj = Wo[j], boo = bo[0];

    float h1own = 0.f, h2own = 0.f;
    float azrP = bAzr, ihP = bIh;                  // carried GRU1 h-side partials

    float xA = xbase[0 * 8 + xoff];
    float xB = xbase[1 * 8 + xoff];
    float xC = xbase[2 * 8 + xoff];

#define GSTEP(SS, XCUR, XFILL)                                                   \
    {                                                                            \
        const int s = (SS);                                                      \
        /* h2 fan-out: 15 independent depth-1 DPPs from h2own */                 \
        const float h0 = h2own;                                                  \
        const float t1 = rorkf_<1>(h0),  t2  = rorkf_<2>(h0);                    \
        const float t3 = rorkf_<3>(h0),  t4  = rorkf_<4>(h0);                    \
        const float t5 = rorkf_<5>(h0),  t6  = rorkf_<6>(h0);                    \
        const float t7 = rorkf_<7>(h0),  t8  = rorkf_<8>(h0);                    \
        const float t9 = rorkf_<9>(h0),  t10 = rorkf_<10>(h0);                   \
        const float t11 = rorkf_<11>(h0), t12 = rorkf_<12>(h0);                  \
        const float t13 = rorkf_<13>(h0), t14 = rorkf_<14>(h0);                  \
        const float t15 = rorkf_<15>(h0);                                        \
        float za0 = bA2, ra0 = bB2, ha0 = bC2, da0 = bdj;                        \
        float za1 = 0.f, ra1 = 0.f, ha1 = 0.f, da1 = 0.f;                        \
        za0 = fmaf(h0,  q2z[0], za0);  ra0 = fmaf(h0,  q2r[0], ra0);             \
        ha0 = fmaf(h0,  q2h[0], ha0);  da0 = fmaf(h0,  wdk[0], da0);             \
        za0 = fmaf(t1,  q2z[1], za0);  ra0 = fmaf(t1,  q2r[1], ra0);             \
        ha0 = fmaf(t1,  q2h[1], ha0);  da0 = fmaf(t1,  wdk[1], da0);             \
        za0 = fmaf(t2,  q2z[2], za0);  ra0 = fmaf(t2,  q2r[2], ra0);             \
        ha0 = fmaf(t2,  q2h[2], ha0);  da0 = fmaf(t2,  wdk[2], da0);             \
        za0 = fmaf(t3,  q2z[3], za0);  ra0 = fmaf(t3,  q2r[3], ra0);             \
        ha0 = fmaf(t3,  q2h[3], ha0);  da0 = fmaf(t3,  wdk[3], da0);             \
        za0 = fmaf(t4,  q2z[4], za0);  ra0 = fmaf(t4,  q2r[4], ra0);             \
        ha0 = fmaf(t4,  q2h[4], ha0);  da0 = fmaf(t4,  wdk[4], da0);             \
        za0 = fmaf(t5,  q2z[5], za0);  ra0 = fmaf(t5,  q2r[5], ra0);             \
        ha0 = fmaf(t5,  q2h[5], ha0);  da0 = fmaf(t5,  wdk[5], da0);             \
        za0 = fmaf(t6,  q2z[6], za0);  ra0 = fmaf(t6,  q2r[6], ra0);             \
        ha0 = fmaf(t6,  q2h[6], ha0);  da0 = fmaf(t6,  wdk[6], da0);             \
        za0 = fmaf(t7,  q2z[7], za0);  ra0 = fmaf(t7,  q2r[7], ra0);             \
        ha0 = fmaf(t7,  q2h[7], ha0);  da0 = fmaf(t7,  wdk[7], da0);             \
        za1 = fmaf(t8,  q2z[8], za1);  ra1 = fmaf(t8,  q2r[8], ra1);             \
        ha1 = fmaf(t8,  q2h[8], ha1);  da1 = fmaf(t8,  wdk[8], da1);             \
        za1 = fmaf(t9,  q2z[9], za1);  ra1 = fmaf(t9,  q2r[9], ra1);             \
        ha1 = fmaf(t9,  q2h[9], ha1);  da1 = fmaf(t9,  wdk[9], da1);             \
        za1 = fmaf(t10, q2z[10], za1); ra1 = fmaf(t10, q2r[10], ra1);            \
        ha1 = fmaf(t10, q2h[10], ha1); da1 = fmaf(t10, wdk[10], da1);            \
        za1 = fmaf(t11, q2z[11], za1); ra1 = fmaf(t11, q2r[11], ra1);            \
        ha1 = fmaf(t11, q2h[11], ha1); da1 = fmaf(t11, wdk[11], da1);            \
        za1 = fmaf(t12, q2z[12], za1); ra1 = fmaf(t12, q2r[12], ra1);            \
        ha1 = fmaf(t12, q2h[12], ha1); da1 = fmaf(t12, wdk[12], da1);            \
        za1 = fmaf(t13, q2z[13], za1); ra1 = fmaf(t13, q2r[13], ra1);            \
        ha1 = fmaf(t13, q2h[13], ha1); da1 = fmaf(t13, wdk[13], da1);            \
        za1 = fmaf(t14, q2z[14], za1); ra1 = fmaf(t14, q2r[14], ra1);            \
        ha1 = fmaf(t14, q2h[14], ha1); da1 = fmaf(t14, wdk[14], da1);            \
        za1 = fmaf(t15, q2z[15], za1); ra1 = fmaf(t15, q2r[15], ra1);            \
        ha1 = fmaf(t15, q2h[15], ha1); da1 = fmaf(t15, wdk[15], da1);            \
        /* x fan-out: 7 depth-1 DPPs from XCUR */                                \
        const float x0 = XCUR;                                                   \
        const float u1v = rorkf_<1>(x0), u2v = rorkf_<2>(x0);                    \
        const float u3v = rorkf_<3>(x0), u4v = rorkf_<4>(x0);                    \
        const float u5v = rorkf_<5>(x0), u6v = rorkf_<6>(x0);                    \
        const float u7v = rorkf_<7>(x0);                                         \
        float ax0 = azrP, ax1 = 0.f, gh0 = bGh, gh1 = 0.f;                       \
        ax0 = fmaf(x0,  Ax[0], ax0);  gh0 = fmaf(x0,  Wx[0], gh0);               \
        ax0 = fmaf(u1v, Ax[1], ax0);  gh0 = fmaf(u1v, Wx[1], gh0);               \
        ax0 = fmaf(u2v, Ax[2], ax0);  gh0 = fmaf(u2v, Wx[2], gh0);               \
        ax0 = fmaf(u3v, Ax[3], ax0);  gh0 = fmaf(u3v, Wx[3], gh0);               \
        ax1 = fmaf(u4v, Ax[4], ax1);  gh1 = fmaf(u4v, Wx[4], gh1);               \
        ax1 = fmaf(u5v, Ax[5], ax1);  gh1 = fmaf(u5v, Wx[5], gh1);               \
        ax1 = fmaf(u6v, Ax[6], ax1);  gh1 = fmaf(u6v, Wx[6], gh1);               \
        ax1 = fmaf(u7v, Ax[7], ax1);  gh1 = fmaf(u7v, Wx[7], gh1);               \
        XFILL = xbase[((s + 3) & (TT - 1)) * 8 + xoff];  /* prefetch s+3 */      \
        /* GRU1: pair swap gives both z and r pre-activations */                 \
        const float azrC = ax0 + ax1;                                            \
        const float swp = rorkf_<8>(azrC);                                       \
        const float s_own = sgm_(azrC), s_sw = sgm_(swp);                        \
        const float z1 = ishi ? s_sw : s_own;                                    \
        const float r1 = ishi ? s_own : s_sw;                                    \
        const float hh1 = fmaxf(fmaf(r1, ihP, gh0 + gh1), 0.f);                  \
        h1own = fmaf(z1, h1own - hh1, hh1);                                      \
        /* h1 fan-out: W2 taps + next-step GRU1 h-taps */                        \
        const float n0 = h1own;                                                  \
        const float n1 = rorkf_<1>(n0), n2 = rorkf_<2>(n0);                      \
        const float n3 = rorkf_<3>(n0), n4 = rorkf_<4>(n0);                      \
        const float n5 = rorkf_<5>(n0), n6 = rorkf_<6>(n0);                      \
        const float n7 = rorkf_<7>(n0);                                          \
        float hb0 = bD2, hb1 = 0.f;                                              \
        float aN0 = bAzr, aN1 = 0.f, iN0 = bIh, iN1 = 0.f;                       \
        za0 = fmaf(n0, p2z[0], za0);  ra0 = fmaf(n0, p2r[0], ra0);               \
        hb0 = fmaf(n0, p2h[0], hb0);                                             \
        aN0 = fmaf(n0, Ch[0], aN0);   iN0 = fmaf(n0, Qh[0], iN0);                \
        za1 = fmaf(n1, p2z[1], za1);  ra1 = fmaf(n1, p2r[1], ra1);               \
        hb1 = fmaf(n1, p2h[1], hb1);                                             \
        aN1 = fmaf(n1, Ch[1], aN1);   iN1 = fmaf(n1, Qh[1], iN1);                \
        za0 = fmaf(n2, p2z[2], za0);  ra0 = fmaf(n2, p2r[2], ra0);               \
        hb0 = fmaf(n2, p2h[2], hb0);                                             \
        aN0 = fmaf(n2, Ch[2], aN0);   iN0 = fmaf(n2, Qh[2], iN0);                \
        za1 = fmaf(n3, p2z[3], za1);  ra1 = fmaf(n3, p2r[3], ra1);               \
        hb1 = fmaf(n3, p2h[3], hb1);                                             \
        aN1 = fmaf(n3, Ch[3], aN1);   iN1 = fmaf(n3, Qh[3], iN1);                \
        za0 = fmaf(n4, p2z[4], za0);  ra0 = fmaf(n4, p2r[4], ra0);               \
        hb0 = fmaf(n4, p2h[4], hb0);                                             \
        aN0 = fmaf(n4, Ch[4], aN0);   iN0 = fmaf(n4, Qh[4], iN0);                \
        za1 = fmaf(n5, p2z[5], za1);  ra1 = fmaf(n5, p2r[5], ra1);               \
        hb1 = fmaf(n5, p2h[5], hb1);                                             \
        aN1 = fmaf(n5, Ch[5], aN1);   iN1 = fmaf(n5, Qh[5], iN1);                \
        za0 = fmaf(n6, p2z[6], za0);  ra0 = fmaf(n6, p2r[6], ra0);               \
        hb0 = fmaf(n6, p2h[6], hb0);                                             \
        aN0 = fmaf(n6, Ch[6], aN0);   iN0 = fmaf(n6, Qh[6], iN0);                \
        za1 = fmaf(n7, p2z[7], za1);  ra1 = fmaf(n7, p2r[7], ra1);               \
        hb1 = fmaf(n7, p2h[7], hb1);                                             \
        aN1 = fmaf(n7, Ch[7], aN1);   iN1 = fmaf(n7, Qh[7], iN1);                \
        azrP = aN0 + aN1;  ihP = iN0 + iN1;                                      \
        /* GRU2 nonlinearity + state */                                          \
        const float zaC = za0 + za1, raC = ra0 + ra1;                            \
        const float haC = ha0 + ha1, hbC = hb0 + hb1;                            \
        const float z2 = sgm_(zaC), r2 = sgm_(raC);                              \
        const float hh2 = fmaxf(fmaf(r2, haC, hbC), 0.f);                        \
        h2own = fmaf(z2, h2own - hh2, hh2);                                      \
        /* dense for step s-1 (da used h2(s-1)) */                               \
        float e = fmaxf(da0 + da1, 0.f) * woj;                                   \
        e += shrf_<0x118>(e);                                                    \
        e += shrf_<0x114>(e);                                                    \
        e += shrf_<0x112>(e);                                                    \
        e += shrf_<0x111>(e);                                                    \
        if (s > 0) { if (isw) outrow[s - 1] = e + boo; }                         \
    }

    for (int s0 = 0; s0 < TT; s0 += 4) {
        GSTEP(s0 + 0, xA, xA)
        GSTEP(s0 + 1, xB, xB)
        GSTEP(s0 + 2, xC, xC)
        GSTEP(s0 + 3, xA, xA)
        { float t = xB; xB = xC; xC = xA; xA = t; }
    }
#undef GSTEP

    // epilogue: dense for s = 511 from final h2 (fan-out, off-loop)
    {
        const float h0 = h2own;
        float da0 = fmaf(h0, wdk[0], bdj), da1 = 0.f;
        const float t1 = rorkf_<1>(h0),  t2  = rorkf_<2>(h0);
        const float t3 = rorkf_<3>(h0),  t4  = rorkf_<4>(h0);
        const float t5 = rorkf_<5>(h0),  t6  = rorkf_<6>(h0);
        const float t7 = rorkf_<7>(h0),  t8  = rorkf_<8>(h0);
        const float t9 = rorkf_<9>(h0),  t10 = rorkf_<10>(h0);
        const float t11 = rorkf_<11>(h0), t12 = rorkf_<12>(h0);
        const float t13 = rorkf_<13>(h0), t14 = rorkf_<14>(h0);
        const float t15 = rorkf_<15>(h0);
        da0 = fmaf(t1, wdk[1], da0);   da1 = fmaf(t2, wdk[2], da1);
        da0 = fmaf(t3, wdk[3], da0);   da1 = fmaf(t4, wdk[4], da1);
        da0 = fmaf(t5, wdk[5], da0);   da1 = fmaf(t6, wdk[6], da1);
        da0 = fmaf(t7, wdk[7], da0);   da1 = fmaf(t8, wdk[8], da1);
        da0 = fmaf(t9, wdk[9], da0);   da1 = fmaf(t10, wdk[10], da1);
        da0 = fmaf(t11, wdk[11], da0); da1 = fmaf(t12, wdk[12], da1);
        da0 = fmaf(t13, wdk[13], da0); da1 = fmaf(t14, wdk[14], da1);
        da0 = fmaf(t15, wdk[15], da0);
        float e = fmaxf(da0 + da1, 0.f) * woj;
        e += shrf_<0x118>(e);
        e += shrf_<0x114>(e);
        e += shrf_<0x112>(e);
        e += shrf_<0x111>(e);
        if (isw) outrow[TT - 1] = e + boo;
    }
}

extern "C" void kernel_launch(void* const* d_in, const int* in_sizes, int n_in,
                              void* d_out, int out_size, void* d_ws, size_t ws_size,
                              hipStream_t stream) {
    const float* x   = (const float*)d_in[0];
    const float* W1  = (const float*)d_in[1];
    const float* Ur1 = (const float*)d_in[2];
    const float* b1  = (const float*)d_in[3];
    const float* W2  = (const float*)d_in[4];
    const float* Ur2 = (const float*)d_in[5];
    const float* b2  = (const float*)d_in[6];
    const float* Wd  = (const float*)d_in[7];
    const float* bd  = (const float*)d_in[8];
    const float* Wo  = (const float*)d_in[9];
    const float* bo  = (const float*)d_in[10];
    float* out = (float*)d_out;

    dim3 grid(4096 / 4);   // 1024 waves = 1/SIMD
    dim3 block(64);        // 4 rows x 16 lanes, zero LDS
    gru_fan<<<grid, block, 0, stream>>>(x, W1, Ur1, b1, W2, Ur2, b2,
                                        Wd, bd, Wo, bo, out);
}